// Round 7
// baseline (756.639 us; speedup 1.0000x reference)
//
#include <hip/hip_runtime.h>

#define N_G   15135
#define E_N   242160
#define BSZ   8
#define K_TOP 7568
#define NH    128
#define NBIN  65536
#define SUFS  65600  // suf stride (65537 rounded up)

// ---------------- utility ----------------
__global__ void zero_kernel(int* __restrict__ p, int n) {
  int i = blockIdx.x * 1024 + threadIdx.x;
  if (i < n) p[i] = 0;
}

__global__ void count_kernel(const int* __restrict__ ei, int* __restrict__ cnt) {
  int e = blockIdx.x * 256 + threadIdx.x;
  if (e < E_N) atomicAdd(&cnt[ei[E_N + e]], 1);
}

// per-chunk local scan + atomic ticket for block base; also dinv and 1/||topk_w||.
__global__ __launch_bounds__(1024) void scan_kernel(const int* __restrict__ cnt,
                                                    int* __restrict__ rowstart,
                                                    float* __restrict__ dinv,
                                                    int* __restrict__ gctr,
                                                    const float* __restrict__ topk_w,
                                                    float* __restrict__ scal) {
  __shared__ int buf[1024];
  __shared__ int base;
  int tid = threadIdx.x;
  int i = blockIdx.x * 1024 + tid;
  int v = (i < N_G) ? cnt[i] : 0;
  if (i < N_G) dinv[i] = 1.0f / sqrtf((float)(v + 1));  // +1 = self loop
  buf[tid] = v;
  __syncthreads();
  for (int s = 1; s < 1024; s <<= 1) {
    int t = (tid >= s) ? buf[tid - s] : 0;
    __syncthreads();
    buf[tid] += t;
    __syncthreads();
  }
  if (tid == 1023) base = atomicAdd(gctr, buf[1023]);
  __syncthreads();
  if (i < N_G) rowstart[i] = base + buf[tid] - v;
  if (blockIdx.x == 0) {
    __shared__ float fbuf[512];
    if (tid < 512) {
      float w = (tid < 384) ? topk_w[tid] : 0.f;
      fbuf[tid] = w * w;
    }
    __syncthreads();
    for (int s = 256; s > 0; s >>= 1) {
      if (tid < s) fbuf[tid] += fbuf[tid + s];
      __syncthreads();
    }
    if (tid == 0) scal[0] = 1.0f / sqrtf(fbuf[0]);
  }
}

__global__ void fill_kernel(const int* __restrict__ ei, const int* __restrict__ rowstart,
                            int* __restrict__ fillc, int* __restrict__ csr) {
  int e = blockIdx.x * 256 + threadIdx.x;
  if (e < E_N) {
    int s = ei[e], d = ei[E_N + e];
    int pos = rowstart[d] + atomicAdd(&fillc[d], 1);
    csr[pos] = s;
  }
}

// ---------------- dense matmul: out[M][128] = A[M][CIN] @ W[CIN][128] ----------------
template<int CIN>
__global__ __launch_bounds__(256, 6) void mm_kernel(const float* __restrict__ A,
                                                    const float* __restrict__ W,
                                                    float* __restrict__ out, int M) {
  __shared__ float Bst[32][132];  // [kk][col]
  __shared__ float Ast2[32][68];  // [kk][row]
  int tid = threadIdx.x;
  int rb0 = blockIdx.x * 64;
  int c0 = (tid & 31) * 4;
  int r0 = (tid >> 5) * 8;
  float acc[8][4];
#pragma unroll
  for (int i = 0; i < 8; i++)
#pragma unroll
    for (int j = 0; j < 4; j++) acc[i][j] = 0.f;

  for (int k0 = 0; k0 < CIN; k0 += 32) {
    {
      int koff = (tid & 7) * 4;
      int row = tid >> 3;  // 0..31
#pragma unroll
      for (int p = 0; p < 2; ++p) {
        int r = row + p * 32;
        int grow = rb0 + r;
        float4 v = make_float4(0.f, 0.f, 0.f, 0.f);
        if (grow < M) v = *(const float4*)(A + (size_t)grow * CIN + k0 + koff);
        Ast2[koff + 0][r] = v.x; Ast2[koff + 1][r] = v.y;
        Ast2[koff + 2][r] = v.z; Ast2[koff + 3][r] = v.w;
      }
    }
    {
      int cc = (tid & 31) * 4;
      int kr = tid >> 5;  // 0..7
#pragma unroll
      for (int p = 0; p < 4; ++p) {
        int k = kr + p * 8;
        *(float4*)&Bst[k][cc] = *(const float4*)(W + (size_t)(k0 + k) * NH + cc);
      }
    }
    __syncthreads();
#pragma unroll 4
    for (int kk = 0; kk < 32; ++kk) {
      float a[8], b[4];
      *(float4*)&a[0] = *(const float4*)&Ast2[kk][r0];
      *(float4*)&a[4] = *(const float4*)&Ast2[kk][r0 + 4];
      *(float4*)&b[0] = *(const float4*)&Bst[kk][c0];
#pragma unroll
      for (int i = 0; i < 8; i++)
#pragma unroll
        for (int j = 0; j < 4; j++)
          acc[i][j] = fmaf(a[i], b[j], acc[i][j]);
    }
    __syncthreads();
  }
#pragma unroll
  for (int i = 0; i < 8; i++) {
    int row = rb0 + r0 + i;
    if (row < M)
      *(float4*)(out + (size_t)row * NH + c0) = make_float4(acc[i][0], acc[i][1], acc[i][2], acc[i][3]);
  }
}

// ---------------- sparse aggregation, channel-half (64 ch/wave) ----------------
// One dispatch per (layer, half): XCD b works batch b, half fixed ->
// gather working set 15135*256B = 3.87 MB < 4 MiB per-XCD L2.
__global__ __launch_bounds__(256) void agg_half_kernel(const float* __restrict__ hw,
                                                       const int* __restrict__ csr,
                                                       const int* __restrict__ rowstart,
                                                       const int* __restrict__ cnt,
                                                       const float* __restrict__ dinv,
                                                       const float* __restrict__ bias,
                                                       float* __restrict__ hout, int half) {
  int b = blockIdx.x & 7;
  int chunk = blockIdx.x >> 3;
  int wave = threadIdx.x >> 6, lane = threadIdx.x & 63;
  int d = chunk * 4 + wave;
  if (d >= N_G) return;
  d = __builtin_amdgcn_readfirstlane(d);
  int c = (half << 6) + lane;
  const float* hwb = hw + (size_t)b * N_G * NH;
  float dv = dinv[d];
  int e0 = rowstart[d];
  int n = cnt[d];
  const int* ce = csr + e0;
  float a0 = dv * hwb[(size_t)d * NH + c];
  float a1 = 0.f, a2 = 0.f, a3 = 0.f, a4 = 0.f, a5 = 0.f, a6 = 0.f, a7 = 0.f;
  int l = 0;
  for (; l + 8 <= n; l += 8) {
    int s0 = ce[l+0], s1 = ce[l+1], s2 = ce[l+2], s3 = ce[l+3];
    int s4 = ce[l+4], s5 = ce[l+5], s6 = ce[l+6], s7 = ce[l+7];
    float w0 = dinv[s0], w1 = dinv[s1], w2 = dinv[s2], w3 = dinv[s3];
    float w4 = dinv[s4], w5 = dinv[s5], w6 = dinv[s6], w7 = dinv[s7];
    float v0 = hwb[(size_t)s0 * NH + c];
    float v1 = hwb[(size_t)s1 * NH + c];
    float v2 = hwb[(size_t)s2 * NH + c];
    float v3 = hwb[(size_t)s3 * NH + c];
    float v4 = hwb[(size_t)s4 * NH + c];
    float v5 = hwb[(size_t)s5 * NH + c];
    float v6 = hwb[(size_t)s6 * NH + c];
    float v7 = hwb[(size_t)s7 * NH + c];
    a0 = fmaf(w0, v0, a0); a1 = fmaf(w1, v1, a1);
    a2 = fmaf(w2, v2, a2); a3 = fmaf(w3, v3, a3);
    a4 = fmaf(w4, v4, a4); a5 = fmaf(w5, v5, a5);
    a6 = fmaf(w6, v6, a6); a7 = fmaf(w7, v7, a7);
  }
  for (; l < n; ++l) {
    int s = ce[l];
    a0 = fmaf(dinv[s], hwb[(size_t)s * NH + c], a0);
  }
  float s = ((a0 + a1) + (a2 + a3)) + ((a4 + a5) + (a6 + a7));
  float r = fmaxf(fmaf(dv, s, bias[c]), 0.f);
  hout[((size_t)b * N_G + d) * NH + c] = r;
}

// ---------------- layer-3 half-agg fused with partial score/fc dots ----------------
// h3 never stored; per (row, half) writes 2 partial dots.
__global__ __launch_bounds__(256) void agg_score_half_kernel(const float* __restrict__ hw,
                                                             const int* __restrict__ csr,
                                                             const int* __restrict__ rowstart,
                                                             const int* __restrict__ cnt,
                                                             const float* __restrict__ dinv,
                                                             const float* __restrict__ bias,
                                                             const float* __restrict__ h1,
                                                             const float* __restrict__ h2,
                                                             const float* __restrict__ topk_w,
                                                             const float* __restrict__ fcW,
                                                             float* __restrict__ pd1,
                                                             float* __restrict__ pd2,
                                                             int half) {
  int b = blockIdx.x & 7;
  int chunk = blockIdx.x >> 3;
  int wave = threadIdx.x >> 6, lane = threadIdx.x & 63;
  int d = chunk * 4 + wave;
  if (d >= N_G) return;
  d = __builtin_amdgcn_readfirstlane(d);
  int c = (half << 6) + lane;
  const float* hwb = hw + (size_t)b * N_G * NH;
  float dv = dinv[d];
  int e0 = rowstart[d];
  int n = cnt[d];
  const int* ce = csr + e0;
  float a0 = dv * hwb[(size_t)d * NH + c];
  float a1 = 0.f, a2 = 0.f, a3 = 0.f, a4 = 0.f, a5 = 0.f, a6 = 0.f, a7 = 0.f;
  int l = 0;
  for (; l + 8 <= n; l += 8) {
    int s0 = ce[l+0], s1 = ce[l+1], s2 = ce[l+2], s3 = ce[l+3];
    int s4 = ce[l+4], s5 = ce[l+5], s6 = ce[l+6], s7 = ce[l+7];
    float w0 = dinv[s0], w1 = dinv[s1], w2 = dinv[s2], w3 = dinv[s3];
    float w4 = dinv[s4], w5 = dinv[s5], w6 = dinv[s6], w7 = dinv[s7];
    float v0 = hwb[(size_t)s0 * NH + c];
    float v1 = hwb[(size_t)s1 * NH + c];
    float v2 = hwb[(size_t)s2 * NH + c];
    float v3 = hwb[(size_t)s3 * NH + c];
    float v4 = hwb[(size_t)s4 * NH + c];
    float v5 = hwb[(size_t)s5 * NH + c];
    float v6 = hwb[(size_t)s6 * NH + c];
    float v7 = hwb[(size_t)s7 * NH + c];
    a0 = fmaf(w0, v0, a0); a1 = fmaf(w1, v1, a1);
    a2 = fmaf(w2, v2, a2); a3 = fmaf(w3, v3, a3);
    a4 = fmaf(w4, v4, a4); a5 = fmaf(w5, v5, a5);
    a6 = fmaf(w6, v6, a6); a7 = fmaf(w7, v7, a7);
  }
  for (; l < n; ++l) {
    int s = ce[l];
    a0 = fmaf(dinv[s], hwb[(size_t)s * NH + c], a0);
  }
  float s = ((a0 + a1) + (a2 + a3)) + ((a4 + a5) + (a6 + a7));
  float r = fmaxf(fmaf(dv, s, bias[c]), 0.f);
  // partial dots in xc feature order f = c*3 + layer
  size_t rbase = ((size_t)b * N_G + d) * NH + c;
  float u1 = h1[rbase];
  float u2 = h2[rbase];
  float d1 = u1 * topk_w[c * 3] + u2 * topk_w[c * 3 + 1] + r * topk_w[c * 3 + 2];
  float d2 = u1 * fcW[c * 3]    + u2 * fcW[c * 3 + 1]    + r * fcW[c * 3 + 2];
#pragma unroll
  for (int sh = 32; sh > 0; sh >>= 1) {
    d1 += __shfl_down(d1, sh);
    d2 += __shfl_down(d2, sh);
  }
  if (lane == 0) {
    int gw = b * N_G + d;
    pd1[gw * 2 + half] = d1;
    pd2[gw * 2 + half] = d2;
  }
}

// ---------------- combine halves -> score/key + histogram ----------------
__global__ void combine_kernel(const float* __restrict__ pd1, const float* __restrict__ pd2,
                               const float* __restrict__ scal, float* __restrict__ score,
                               float* __restrict__ d2a, unsigned* __restrict__ keys,
                               int* __restrict__ hist) {
  int b = blockIdx.y;
  int i = blockIdx.x * 256 + threadIdx.x;
  if (i >= N_G) return;
  int gw = b * N_G + i;
  float d1 = pd1[2 * gw] + pd1[2 * gw + 1];
  float d2 = pd2[2 * gw] + pd2[2 * gw + 1];
  float sc = tanhf(d1 * scal[0]);
  score[gw] = sc;
  d2a[gw] = d2;
  unsigned u = __float_as_uint(sc);
  unsigned k32 = (u & 0x80000000u) ? ~u : (u | 0x80000000u);  // monotone float->u32
  keys[gw] = k32;
  atomicAdd(&hist[b * NBIN + (int)(k32 >> 16)], 1);
}

// ---------------- per-batch suffix sums over 65536 bins ----------------
// suf[b][bin] = #{keys with bin' >= bin}; suf[b][65536] = 0.
__global__ __launch_bounds__(1024) void suffix_kernel(const int* __restrict__ hist,
                                                      int* __restrict__ suf) {
  __shared__ int buf[1024];
  int b = blockIdx.x;
  const int* hb = hist + b * NBIN;
  int* sb = suf + b * SUFS;
  int t = threadIdx.x;
  int base = t * 64;
  int s = 0;
  for (int k = 0; k < 64; ++k) s += hb[base + k];
  buf[t] = s;
  __syncthreads();
  for (int off = 1; off < 1024; off <<= 1) {
    int v = (t + off < 1024) ? buf[t + off] : 0;
    __syncthreads();
    buf[t] += v;
    __syncthreads();
  }
  int acc = buf[t] - s;  // keys in chunks above
  if (t == 0) sb[NBIN] = 0;
  for (int k = 63; k >= 0; --k) {
    acc += hb[base + k];
    sb[base + k] = acc;
  }
}

// ---------------- bucket scatter (consumes hist via atomicSub) ----------------
__global__ void scatter_kernel(const unsigned* __restrict__ keys, int* __restrict__ hist,
                               const int* __restrict__ suf, int2* __restrict__ bucket) {
  int b = blockIdx.y;
  int i = blockIdx.x * 256 + threadIdx.x;
  if (i >= N_G) return;
  unsigned k = keys[b * N_G + i];
  int bin = (int)(k >> 16);
  int old = atomicSub(&hist[b * NBIN + bin], 1);
  int pos = suf[b * SUFS + bin + 1] + old - 1;
  bucket[b * N_G + pos] = make_int2((int)k, i);
}

// ---------------- exact stable-descending rank + z scatter ----------------
__global__ void rank_z_kernel(const unsigned* __restrict__ keys, const int* __restrict__ suf,
                              const int2* __restrict__ bucket, const float* __restrict__ score,
                              const float* __restrict__ d2a, const float* __restrict__ fcb,
                              float* __restrict__ z) {
  int b = blockIdx.y;
  int i = blockIdx.x * 256 + threadIdx.x;
  if (i >= N_G) return;
  int gw = b * N_G + i;
  unsigned k = keys[gw];
  int bin = (int)(k >> 16);
  int lo = suf[b * SUFS + bin + 1];
  int hi = suf[b * SUFS + bin];
  int r = lo;
  const int2* bk = bucket + b * N_G;
  for (int p = lo; p < hi; ++p) {
    int2 e = bk[p];
    unsigned kj = (unsigned)e.x;
    r += (kj > k || (kj == k && e.y < i)) ? 1 : 0;
  }
  if (r < K_TOP) z[b * K_TOP + r] = fmaf(score[gw], d2a[gw], fcb[0]);
}

// ---------------- lin1: hpre[b][c] += sum_r z[b][r]*W[r][c] (r-split + atomics) ----------------
__global__ __launch_bounds__(256) void lin1_kernel(const float* __restrict__ z,
                                                   const float* __restrict__ W,
                                                   float* __restrict__ hpre) {
  __shared__ float zb[237];
  int b = blockIdx.y, rs = blockIdx.x;
  int r0 = rs * 237;
  int rn = K_TOP - r0; if (rn > 237) rn = 237;
  for (int q = threadIdx.x; q < rn; q += 256) zb[q] = z[b * K_TOP + r0 + q];
  __syncthreads();
  int c = threadIdx.x;
  float a0 = 0.f, a1 = 0.f;
  for (int r = 0; r < rn; ++r) {
    float zz = zb[r];
    const float* wr = W + (size_t)(r0 + r) * 512;
    a0 = fmaf(zz, wr[c], a0);
    a1 = fmaf(zz, wr[c + 256], a1);
  }
  atomicAdd(&hpre[b * 512 + c], a0);
  atomicAdd(&hpre[b * 512 + c + 256], a1);
}

// ---------------- lin2 + log_softmax ----------------
__global__ __launch_bounds__(128) void lin2_kernel(const float* __restrict__ hpre,
                                                   const float* __restrict__ l1b,
                                                   const float* __restrict__ W2,
                                                   const float* __restrict__ l2b,
                                                   float* __restrict__ out) {
  int b = blockIdx.x, tid = threadIdx.x;
  float a0 = 0.f, a1 = 0.f;
  for (int j = tid; j < 512; j += 128) {
    float t = fmaxf(hpre[b * 512 + j] + l1b[j], 0.f);
    a0 = fmaf(t, W2[j * 2 + 0], a0);
    a1 = fmaf(t, W2[j * 2 + 1], a1);
  }
#pragma unroll
  for (int s = 32; s > 0; s >>= 1) {
    a0 += __shfl_down(a0, s);
    a1 += __shfl_down(a1, s);
  }
  __shared__ float red[2][2];
  if ((tid & 63) == 0) { red[tid >> 6][0] = a0; red[tid >> 6][1] = a1; }
  __syncthreads();
  if (tid == 0) {
    float l0 = red[0][0] + red[1][0] + l2b[0];
    float l1 = red[0][1] + red[1][1] + l2b[1];
    float m = fmaxf(l0, l1);
    float lse = m + logf(expf(l0 - m) + expf(l1 - m));
    out[b * 2 + 0] = l0 - lse;
    out[b * 2 + 1] = l1 - lse;
  }
}

extern "C" void kernel_launch(void* const* d_in, const int* in_sizes, int n_in,
                              void* d_out, int out_size, void* d_ws, size_t ws_size,
                              hipStream_t stream) {
  const float* x   = (const float*)d_in[0];
  const int*   ei  = (const int*)d_in[2];
  const float* W1  = (const float*)d_in[3];
  const float* b1  = (const float*)d_in[4];
  const float* W2  = (const float*)d_in[5];
  const float* b2  = (const float*)d_in[6];
  const float* W3  = (const float*)d_in[7];
  const float* b3  = (const float*)d_in[8];
  const float* tkw = (const float*)d_in[9];
  const float* fcW = (const float*)d_in[10];
  const float* fcb = (const float*)d_in[11];
  const float* l1W = (const float*)d_in[12];
  const float* l1b = (const float*)d_in[13];
  const float* l2W = (const float*)d_in[14];
  const float* l2b = (const float*)d_in[15];
  float* out = (float*)d_out;

  char* ws = (char*)d_ws;
  size_t off = 0;
  auto alloc = [&](size_t bytes) {
    char* p = ws + off;
    off += (bytes + 255) & ~(size_t)255;
    return p;
  };
  // zero-init region (contiguous): cnt, fillc, gctr, hpre, hist
  int*   cnt   = (int*)alloc(15136 * 4);
  int*   fillc = (int*)alloc(15136 * 4);
  int*   gctr  = (int*)alloc(256);
  float* hpre  = (float*)alloc(4096 * 4);
  int*   hist  = (int*)alloc((size_t)BSZ * NBIN * 4);
  // --- end zero region ---
  int*   rowstart = (int*)alloc(15136 * 4);
  float* dinv  = (float*)alloc(15136 * 4);
  float* scal  = (float*)alloc(64);
  float* z     = (float*)alloc((size_t)BSZ * K_TOP * 4);
  float* score = (float*)alloc(121088 * 4);
  float* d2a   = (float*)alloc(121088 * 4);
  unsigned* keys = (unsigned*)alloc(121088 * 4);
  int*   suf   = (int*)alloc((size_t)BSZ * SUFS * 4);
  int2*  bucket = (int2*)alloc(121088 * 8);
  float* pd1   = (float*)alloc(121088 * 2 * 4);
  float* pd2   = (float*)alloc(121088 * 2 * 4);
  int*   csr   = (int*)alloc((size_t)E_N * 4);
  float* hw = (float*)alloc((size_t)BSZ * N_G * NH * 4);
  float* h1 = (float*)alloc((size_t)BSZ * N_G * NH * 4);
  float* h2 = (float*)alloc((size_t)BSZ * N_G * NH * 4);
  (void)ws_size; (void)in_sizes; (void)n_in; (void)out_size;

  int zero_n = (int)(((char*)rowstart - (char*)cnt) / 4);
  zero_kernel<<<(zero_n + 1023) / 1024, 1024, 0, stream>>>(cnt, zero_n);
  count_kernel<<<(E_N + 255) / 256, 256, 0, stream>>>(ei, cnt);
  scan_kernel<<<(N_G + 1023) / 1024, 1024, 0, stream>>>(cnt, rowstart, dinv, gctr, tkw, scal);
  fill_kernel<<<(E_N + 255) / 256, 256, 0, stream>>>(ei, rowstart, fillc, csr);

  int M = BSZ * N_G;
  dim3 mmg((M + 63) / 64);
  int aggblocks = 8 * ((N_G + 3) / 4);

  mm_kernel<64><<<mmg, 256, 0, stream>>>(x, W1, hw, M);
  agg_half_kernel<<<aggblocks, 256, 0, stream>>>(hw, csr, rowstart, cnt, dinv, b1, h1, 0);
  agg_half_kernel<<<aggblocks, 256, 0, stream>>>(hw, csr, rowstart, cnt, dinv, b1, h1, 1);
  mm_kernel<128><<<mmg, 256, 0, stream>>>(h1, W2, hw, M);
  agg_half_kernel<<<aggblocks, 256, 0, stream>>>(hw, csr, rowstart, cnt, dinv, b2, h2, 0);
  agg_half_kernel<<<aggblocks, 256, 0, stream>>>(hw, csr, rowstart, cnt, dinv, b2, h2, 1);
  mm_kernel<128><<<mmg, 256, 0, stream>>>(h2, W3, hw, M);
  agg_score_half_kernel<<<aggblocks, 256, 0, stream>>>(hw, csr, rowstart, cnt, dinv, b3,
                                                       h1, h2, tkw, fcW, pd1, pd2, 0);
  agg_score_half_kernel<<<aggblocks, 256, 0, stream>>>(hw, csr, rowstart, cnt, dinv, b3,
                                                       h1, h2, tkw, fcW, pd1, pd2, 1);

  dim3 ng((N_G + 255) / 256, BSZ);
  combine_kernel<<<ng, 256, 0, stream>>>(pd1, pd2, scal, score, d2a, keys, hist);
  suffix_kernel<<<BSZ, 1024, 0, stream>>>(hist, suf);
  scatter_kernel<<<ng, 256, 0, stream>>>(keys, hist, suf, bucket);
  rank_z_kernel<<<ng, 256, 0, stream>>>(keys, suf, bucket, score, d2a, fcb, z);

  dim3 l1g(32, BSZ);
  lin1_kernel<<<l1g, 256, 0, stream>>>(z, l1W, hpre);
  lin2_kernel<<<BSZ, 128, 0, stream>>>(hpre, l1b, l2W, l2b, out);
}